// Round 5
// baseline (449.327 us; speedup 1.0000x reference)
//
#include <hip/hip_runtime.h>
#include <math.h>

#ifndef M_PI
#define M_PI 3.14159265358979323846
#endif

// ---------------- constants ----------------
#define NSIDE 128
#define NVOX  2097152          // 128^3
#define KBINS 100
#define NFIELDS 16             // 8 pred + 8 target
#define NORMF (27.0f / 2097152.0f)   // LPIX^3 / N^3
#define FSTRIDE ((size_t)65 * 16384) // float2 elems per field in trans (kz-major)

// ws layout (bytes)
#define WS_SUMS_OFF   0                       // float[16*101]
#define WS_CNT_OFF    6464                    // int[101]
#define WS_OCT_OFF    8192                    // uint8[65*65*65], kz-major: oct[c][a][b]
#define WS_TRANS_OFF  282880                  // float2[16 * FSTRIDE] = 136.3 MB

// ---------------- exact numpy binning replication (fp64) ----------------
__device__ __forceinline__ double bin_edge(int i, double start, double step, double stop) {
    if (i == 100) return stop;
    return __dadd_rn(__dmul_rn((double)i, step), start);
}

__device__ __forceinline__ void bin_params(double* start, double* step, double* stop) {
    const double inv   = 1.0 / 384.0;
    const double twopi = 2.0 * M_PI;
    double k1 = __dmul_rn(twopi, __dmul_rn(1.0, inv));
    *start = sqrt(__dadd_rn(__dadd_rn(0.0, 0.0), __dmul_rn(k1, k1)));
    double k64 = __dmul_rn(twopi, __dmul_rn(-64.0, inv));
    double s64 = __dmul_rn(k64, k64);
    *stop = sqrt(__dadd_rn(__dadd_rn(s64, s64), s64));
    *step = (*stop - *start) / 100.0;
}

__device__ int compute_bin(int ix, int iy, int iz) {
    const double inv   = 1.0 / 384.0;
    const double twopi = 2.0 * M_PI;
    double fx = (double)(ix < 64 ? ix : ix - 128);
    double fy = (double)(iy < 64 ? iy : iy - 128);
    double fz = (double)(iz < 64 ? iz : iz - 128);
    double kx = __dmul_rn(twopi, __dmul_rn(fx, inv));
    double ky = __dmul_rn(twopi, __dmul_rn(fy, inv));
    double kz = __dmul_rn(twopi, __dmul_rn(fz, inv));
    double sq = __dadd_rn(__dadd_rn(__dmul_rn(kx, kx), __dmul_rn(ky, ky)), __dmul_rn(kz, kz));
    double kmag = sqrt(sq);
    if (!(kmag > 0.0)) return 100;                   // DC -> dropped bin
    double start, step, stop;
    bin_params(&start, &step, &stop);
    double t = (kmag - start) / step;
    int c = (int)floor(t);
    if (c < -1) c = -1;
    if (c > 100) c = 100;
    while (c < 100 && kmag >= bin_edge(c + 1, start, step, stop)) ++c;
    while (c >= 0 && kmag < bin_edge(c, start, step, stop)) --c;
    if (c < 0) c = 0;
    if (c > 99) c = 99;
    return c;
}

// ---------------- radix-4 DIF FFT (in-place, output digit-reversed) ----------------
// Output slot t holds frequency digrev(t); stages r4(h=32), r4(h=8), r4(h=2), r2(h=1).
#define LDS_FENCE() __asm__ volatile("s_waitcnt lgkmcnt(0)" ::: "memory")

__device__ __forceinline__ int digrev(int t) {   // slot -> frequency
    return ((t >> 5) & 3) | (((t >> 3) & 3) << 2) | (((t >> 1) & 3) << 4) | ((t & 1) << 6);
}
__device__ __forceinline__ int slot_of(int k) {  // frequency -> slot (inverse of digrev)
    return ((k & 3) << 5) | (((k >> 2) & 3) << 3) | (((k >> 4) & 3) << 1) | ((k >> 6) & 1);
}

__device__ __forceinline__ float2 cmul(float2 a, float2 w) {
    return make_float2(a.x * w.x - a.y * w.y, a.x * w.y + a.y * w.x);
}
__device__ __forceinline__ float2 twid(float r) {   // e^{2*pi*i*r}, r in revolutions
    return make_float2(__builtin_amdgcn_cosf(r), __builtin_amdgcn_sinf(r));
}

// One radix-4 DIF butterfly: elements e0 + {0,h,2h,3h} (times stride), twiddle o/L.
__device__ __forceinline__ void r4_bf(float2* p, int stride, int e0, int h, int o, float invL) {
    float2 a0 = p[e0 * stride];
    float2 a1 = p[(e0 + h) * stride];
    float2 a2 = p[(e0 + 2 * h) * stride];
    float2 a3 = p[(e0 + 3 * h) * stride];
    float2 s0 = make_float2(a0.x + a2.x, a0.y + a2.y);
    float2 d0 = make_float2(a0.x - a2.x, a0.y - a2.y);
    float2 s1 = make_float2(a1.x + a3.x, a1.y + a3.y);
    float2 d1 = make_float2(a1.x - a3.x, a1.y - a3.y);
    float2 b0 = make_float2(s0.x + s1.x, s0.y + s1.y);
    float2 b2 = make_float2(s0.x - s1.x, s0.y - s1.y);
    float2 b1 = make_float2(d0.x + d1.y, d0.y - d1.x);   // d0 - i*d1
    float2 b3 = make_float2(d0.x - d1.y, d0.y + d1.x);   // d0 + i*d1
    float r1 = -(float)o * invL;                          // revolutions, exact dyadic
    float2 w1 = twid(r1), w2 = twid(2.0f * r1), w3 = twid(3.0f * r1);
    p[e0 * stride]           = b0;
    p[(e0 + h) * stride]     = cmul(b1, w1);
    p[(e0 + 2 * h) * stride] = cmul(b2, w2);
    p[(e0 + 3 * h) * stride] = cmul(b3, w3);
}

// Final radix-2 stage: two trivial pairs (4bf,4bf+1),(4bf+2,4bf+3), no twiddle.
__device__ __forceinline__ void r2_final(float2* p, int stride, int bf) {
    int j = 4 * bf;
    float2 a0 = p[j * stride], a1 = p[(j + 1) * stride];
    float2 a2 = p[(j + 2) * stride], a3 = p[(j + 3) * stride];
    p[j * stride]       = make_float2(a0.x + a1.x, a0.y + a1.y);
    p[(j + 1) * stride] = make_float2(a0.x - a1.x, a0.y - a1.y);
    p[(j + 2) * stride] = make_float2(a2.x + a3.x, a2.y + a3.y);
    p[(j + 3) * stride] = make_float2(a2.x - a3.x, a2.y - a3.y);
}

// Full 128-pt line FFT, 32 threads per line (bf = 0..31), wave-private line.
__device__ __forceinline__ void fft_line(float2* p, int stride, int bf) {
    r4_bf(p, stride, bf, 32, bf, 1.0f / 128.0f);
    LDS_FENCE();
    { int B = (bf >> 3) * 32, o = bf & 7; r4_bf(p, stride, B + o, 8, o, 1.0f / 32.0f); }
    LDS_FENCE();
    { int B = (bf >> 1) * 8,  o = bf & 1; r4_bf(p, stride, B + o, 2, o, 1.0f / 8.0f); }
    LDS_FENCE();
    r2_final(p, stride, bf);
    LDS_FENCE();
}

// ---------------- kernels ----------------
__global__ __launch_bounds__(256) void k_zero(float* sums, int* counts) {
    int t = blockIdx.x * 256 + threadIdx.x;
    if (t < NFIELDS * 101) sums[t] = 0.0f;
    if (t < 101) counts[t] = 0;
}

// Octant bin table (kz-major: oct[c][a][b]) + exact mode counts.
__global__ __launch_bounds__(256) void k_oct(unsigned char* __restrict__ oct,
                                             int* __restrict__ counts) {
    __shared__ int lcnt[4][104];
    int tid = threadIdx.x;
#pragma unroll
    for (int j = tid; j < 4 * 104; j += 256) ((int*)lcnt)[j] = 0;
    __syncthreads();
    int idx = blockIdx.x * 256 + tid;
    if (idx < 65 * 65 * 65) {
        int c = idx % 65;
        int r = idx / 65;
        int b = r % 65;
        int a = r / 65;
        int id = compute_bin(a, b, c);
        oct[c * 4225 + a * 65 + b] = (unsigned char)id;   // kz-major for plane staging
        if (id < 100) {
            int w = ((a == 0 || a == 64) ? 1 : 2) *
                    ((b == 0 || b == 64) ? 1 : 2) *
                    ((c == 0 || c == 64) ? 1 : 2);
            atomicAdd(&lcnt[tid & 3][id], w);
        }
    }
    __syncthreads();
    if (tid < 101) {
        int tot = lcnt[0][tid] + lcnt[1][tid] + lcnt[2][tid] + lcnt[3][tid];
        if (tot) atomicAdd(&counts[tid], tot);
    }
}

// Pass 0: FFT along z (32 lines/block: fixed x, 32 consecutive y).
// Writes trans[kz][x][y] in natural kz order (via slot_of), kz 0..64 only.
__global__ __launch_bounds__(1024) void k_fft_z(const float* __restrict__ pred,
                                                const float* __restrict__ target,
                                                float2* __restrict__ trans) {
    __shared__ float2 buf[32 * 129];                 // 32 lines, +1 pad
    int t = threadIdx.x;
    int x  = blockIdx.x >> 2;
    int y0 = (blockIdx.x & 3) << 5;
    int f = blockIdx.y;
    const float* in = (f < 8) ? (pred + (size_t)f * NVOX)
                              : (target + (size_t)(f - 8) * NVOX);
    const float* src = in + (size_t)x * 16384 + (size_t)y0 * 128;  // 4096 contiguous floats
#pragma unroll
    for (int i = 0; i < 4; ++i) {
        int n = t + 1024 * i;
        int dy = n >> 7, z = n & 127;
        buf[dy * 129 + z] = make_float2(src[n], 0.0f);
    }
    __syncthreads();
    fft_line(&buf[(t >> 5) * 129], 1, t & 31);       // wave-private pair of lines
    __syncthreads();
    float2* dst = trans + (size_t)f * FSTRIDE;
#pragma unroll
    for (int i = 0; i < 3; ++i) {
        int kk = (t >> 5) + 32 * i;
        int dy = t & 31;
        if (kk <= 64)
            dst[(size_t)kk * 16384 + (size_t)x * 128 + y0 + dy] = buf[dy * 129 + slot_of(kk)];
    }
}

// Pass 1: full 2D 128x128 FFT per (kz, field) plane + power + radial binning.
// Plane is one contiguous 128 KB read. Output order digit-reversed in both dims;
// bin lookup applies digrev. kz weight folds Hermitian symmetry (kz>64 dropped).
__global__ __launch_bounds__(1024) void k_plane(const float2* __restrict__ trans,
                                                const unsigned char* __restrict__ oct,
                                                float* __restrict__ sums) {
    __shared__ float2 P[128 * 129];                  // 132 KB plane, row pad +1
    __shared__ float lbins[4][104];
    __shared__ unsigned char ltab[4225];
    int t = threadIdx.x;
    int kz = blockIdx.x, f = blockIdx.y;
    const float2* src = trans + (size_t)f * FSTRIDE + (size_t)kz * 16384;
    for (int j = t; j < 4 * 104; j += 1024) ((float*)lbins)[j] = 0.0f;
    for (int j = t; j < 4225; j += 1024) ltab[j] = oct[kz * 4225 + j];
    const float4* src4 = (const float4*)src;
#pragma unroll
    for (int i = 0; i < 8; ++i) {                    // load plane, coalesced float4
        int n = t + 1024 * i;                        // 8192 float4 total
        float4 v = src4[n];
        int sx = n >> 6;
        int sy = (n & 63) * 2;
        float2* d = &P[sx * 129 + sy];
        d[0] = make_float2(v.x, v.y);
        d[1] = make_float2(v.z, v.w);
    }
    __syncthreads();
    // y-FFT: rows (stride 1), wave-private, no block barriers inside
    {
        int bf = t & 31, xr = t >> 5;
#pragma unroll
        for (int i = 0; i < 4; ++i)
            fft_line(&P[(xr + 32 * i) * 129], 1, bf);
    }
    __syncthreads();
    // x-FFT: columns (stride 129), cross-wave -> barrier between stages
    {
        int y = t & 127, x8 = t >> 7;
#pragma unroll
        for (int i = 0; i < 4; ++i) { int bf = x8 + 8 * i; r4_bf(P + y, 129, bf, 32, bf, 1.0f / 128.0f); }
        __syncthreads();
#pragma unroll
        for (int i = 0; i < 4; ++i) { int bf = x8 + 8 * i; int B = (bf >> 3) * 32, o = bf & 7; r4_bf(P + y, 129, B + o, 8, o, 1.0f / 32.0f); }
        __syncthreads();
#pragma unroll
        for (int i = 0; i < 4; ++i) { int bf = x8 + 8 * i; int B = (bf >> 1) * 8, o = bf & 1; r4_bf(P + y, 129, B + o, 2, o, 1.0f / 8.0f); }
        __syncthreads();
#pragma unroll
        for (int i = 0; i < 4; ++i) { int bf = x8 + 8 * i; r2_final(P + y, 129, bf); }
    }
    __syncthreads();
    // power + bin (slot -> frequency via digrev)
#pragma unroll
    for (int i = 0; i < 16; ++i) {
        int n = t + 1024 * i;
        int sx = n >> 7, sy = n & 127;
        float2 c = P[sx * 129 + sy];
        float pk = c.x * c.x + c.y * c.y;
        int kx = digrev(sx), ky = digrev(sy);
        int mkx = (kx <= 64) ? kx : 128 - kx;
        int mky = (ky <= 64) ? ky : 128 - ky;
        int id = ltab[mkx * 65 + mky];
        atomicAdd(&lbins[t & 3][id], pk);
    }
    __syncthreads();
    if (t < 101) {
        float wz = (kz == 0 || kz == 64) ? 1.0f : 2.0f;
        float v = lbins[0][t] + lbins[1][t] + lbins[2][t] + lbins[3][t];
        if (v != 0.0f) atomicAdd(&sums[f * 101 + t], v * (NORMF) * wz);
    }
}

// Finalize: Delta^2, log10 ratio, nanmean -> scalar.
__global__ __launch_bounds__(128) void k_finalize(const float* __restrict__ sums,
                                                  const int* __restrict__ counts,
                                                  float* __restrict__ out) {
    __shared__ double ssum[128];
    __shared__ int scnt[128];
    int k = threadIdx.x;
    double local = 0.0;
    int nloc = 0;
    if (k < KBINS) {
        int c = counts[k];
        if (c > 0) {
            double start, step, stop;
            bin_params(&start, &step, &stop);
            double e0 = bin_edge(k, start, step, stop);
            double e1 = bin_edge(k + 1, start, step, stop);
            float kc  = (float)(0.5 * (e0 + e1));    // matches kcent astype(float32)
            float kc3 = kc * kc * kc;                // kc ** 3 in fp32
            const float two_pi2 = (float)(2.0 * M_PI * M_PI);
            float cf = (float)c;
            for (int b = 0; b < 8; ++b) {
                float pm_p = sums[b * 101 + k] / cf;         // pred
                float pm_t = sums[(8 + b) * 101 + k] / cf;   // target
                float dsq_p = pm_p * kc3 / two_pi2;
                float dsq_t = pm_t * kc3 / two_pi2;
                float d = fabsf(log10f(dsq_t) - log10f(dsq_p));
                local += (double)d;
            }
            nloc = 8;
        }
    }
    ssum[k] = local;
    scnt[k] = nloc;
    __syncthreads();
    for (int off = 64; off > 0; off >>= 1) {
        if (k < off) { ssum[k] += ssum[k + off]; scnt[k] += scnt[k + off]; }
        __syncthreads();
    }
    if (k == 0) out[0] = (float)(ssum[0] / (double)scnt[0]);
}

// ---------------- launch ----------------
extern "C" void kernel_launch(void* const* d_in, const int* in_sizes, int n_in,
                              void* d_out, int out_size, void* d_ws, size_t ws_size,
                              hipStream_t stream) {
    (void)in_sizes; (void)n_in; (void)out_size; (void)ws_size;
    const float* pred   = (const float*)d_in[0];
    const float* target = (const float*)d_in[1];
    float* out = (float*)d_out;
    char* ws = (char*)d_ws;

    float* sums        = (float*)(ws + WS_SUMS_OFF);   // [16][101]
    int* counts        = (int*)(ws + WS_CNT_OFF);      // [101]
    unsigned char* oct = (unsigned char*)(ws + WS_OCT_OFF);
    float2* trans      = (float2*)(ws + WS_TRANS_OFF); // [16][65][128][128]

    k_zero<<<7, 256, 0, stream>>>(sums, counts);
    k_oct<<<(65 * 65 * 65 + 255) / 256, 256, 0, stream>>>(oct, counts);

    k_fft_z<<<dim3(512, NFIELDS), 1024, 0, stream>>>(pred, target, trans);
    k_plane<<<dim3(65, NFIELDS), 1024, 0, stream>>>(trans, oct, sums);

    k_finalize<<<1, 128, 0, stream>>>(sums, counts, out);
}